// Round 5
// baseline (920.235 us; speedup 1.0000x reference)
//
#include <hip/hip_runtime.h>

#define TT    512
#define HH    64
#define NB    4
#define NBLK  256
#define HP    72    // h^T pitch in f16 (64 + 8 pad -> 2-way max bank aliasing)

typedef _Float16 f16x8 __attribute__((ext_vector_type(8)));
typedef _Float16 f16x4 __attribute__((ext_vector_type(4)));
typedef float    f32x4 __attribute__((ext_vector_type(4)));

__device__ __forceinline__ float sigmoidf_(float x) {
    return 1.0f / (1.0f + __expf(-x));
}
__device__ __forceinline__ float tanhf_(float x) {
    return 1.0f - 2.0f / (1.0f + __expf(2.0f * x));
}

// 256 blocks x 768 threads (12 waves). Block owns 4 batches (cols 0..3 of a
// 16-col MFMA tile; cols 4..15 are throwaway — matrix pipe is idle anyway).
// Wave W = tid>>6; group = W>>2 (A/B/C); w = W&3.
// Wave w of a group owns M-tiles {w, w+4, w+8, w+12} of the 256-row gate
// matrix => tile g_ = gate g_ of units [16w,16w+16): i,f,g,o of unit u land in
// the SAME lane's accumulators (C/D row = quad*4+reg, col = batch).
// Skew (1 barrier/tick, ticks 0..T+1), same as round 4:
//   A: g1(t) = b1 + W_ih0 x(t) + W_hh0 h1(t-1) -> pointwise -> h1(t)
//   B: p_ih(t) = W_ih1 h1(t-1) -> pis
//   C: g2 = b2 + W_hh1 h2(t-3) + p_ih(t-1) -> pointwise -> h2(t-2)
// Precision: weights as f16 hi + f16 residual (2 MFMAs), fp32 accum/bias/
// pointwise/c; h quantized f16 only across the LDS hop; final h2 kept fp32.
__global__ __launch_bounds__(768) void lstm_mfma(
    const float* __restrict__ x,
    const float* __restrict__ w_ih0, const float* __restrict__ w_hh0,
    const float* __restrict__ b_ih0, const float* __restrict__ b_hh0,
    const float* __restrict__ w_ih1, const float* __restrict__ w_hh1,
    const float* __restrict__ b_ih1, const float* __restrict__ b_hh1,
    const float* __restrict__ w_out, const float* __restrict__ b_out,
    float* __restrict__ out)
{
    __shared__ __align__(16) _Float16 h1T[2][16 * HP];  // h1^T [batch][unit] f16
    __shared__ __align__(16) _Float16 h2T[2][16 * HP];  // h2^T
    __shared__ f32x4 pis[2][1024];                      // B->C partial, fp32 C-layout
    __shared__ float xs[TT * 12];                       // x [t][d][4] fp32
    __shared__ __align__(16) float h2f[16 * 68];        // final h2 fp32 [batch][unit]
    __shared__ float lg[NB][4];

    const int tid   = threadIdx.x;
    const int group = tid >> 8;          // wave-uniform
    const int w     = (tid >> 6) & 3;    // wave-in-group
    const int lane  = tid & 63;
    const int quad  = lane >> 4;
    const int n     = lane & 15;         // MFMA column = batch slot
    const int b0    = blockIdx.x * NB;

    // ---- persistent weight fragments ----
    f16x8 whi[4][2], wlo[4][2], axf[4];
    f32x4 biasf[4];
    {
        const float* Wm = (group == 0) ? w_hh0 : (group == 1) ? w_ih1 : w_hh1;
        const float* bi = (group == 0) ? b_ih0 : b_ih1;
        const float* bh = (group == 0) ? b_hh0 : b_hh1;
        #pragma unroll
        for (int g_ = 0; g_ < 4; ++g_) {
            const int arow = 16 * w + 64 * g_ + n;      // A-frag row: m = lane&15
            #pragma unroll
            for (int k0 = 0; k0 < 2; ++k0) {
                const float* p = Wm + arow * HH + quad * 8 + 32 * k0;
                #pragma unroll
                for (int j = 0; j < 8; ++j) {
                    const float v = p[j];
                    const _Float16 hv = (_Float16)v;
                    whi[g_][k0][j] = hv;
                    wlo[g_][k0][j] = (_Float16)(v - (float)hv);
                }
            }
            #pragma unroll
            for (int r = 0; r < 4; ++r) {               // C/D row = quad*4 + r
                const int crow = 16 * w + 64 * g_ + quad * 4 + r;
                biasf[g_][r] = (group == 1) ? 0.f : (bi[crow] + bh[crow]);
            }
            f16x8 ax;
            #pragma unroll
            for (int j = 0; j < 8; ++j) ax[j] = (_Float16)0.f;
            if (group == 0 && quad == 0) {              // K=3 x-transform, k=0..2
                ax[0] = (_Float16)w_ih0[arow * 3 + 0];
                ax[1] = (_Float16)w_ih0[arow * 3 + 1];
                ax[2] = (_Float16)w_ih0[arow * 3 + 2];
            }
            axf[g_] = ax;
        }
    }

    // ---- LDS init: h buffers zero; preload x slice ----
    for (int i = tid; i < 1152; i += 768) {   // 2 bufs * 16*72 f16 = 1152 ints each
        ((int*)h1T)[i] = 0;
        ((int*)h2T)[i] = 0;
    }
    for (int i = tid; i < TT * 12; i += 768) {
        const int t = i / 12, rem = i - t * 12;
        const int d = rem >> 2, b = rem & 3;
        xs[i] = x[(size_t)(b0 + b) * (TT * 3) + t * 3 + d];
    }
    __syncthreads();

    float creg[4] = {0.f, 0.f, 0.f, 0.f};    // A: c1; C: c2 (4 units/lane)

    for (int t = 0; t <= TT + 1; ++t) {
        if (group == 0) {
            if (t < TT) {
                f16x8 bx;
                #pragma unroll
                for (int j = 0; j < 8; ++j) bx[j] = (_Float16)0.f;
                if (quad == 0) {                      // B[k][n], k=0..2 real
                    const float* xp = xs + t * 12 + (lane & 3);
                    bx[0] = (_Float16)xp[0];
                    bx[1] = (_Float16)xp[4];
                    bx[2] = (_Float16)xp[8];
                }
                const _Float16* hsrc = h1T[(t + 1) & 1];
                const f16x8 bh0 = *(const f16x8*)(hsrc + n * HP + quad * 8);
                const f16x8 bh1 = *(const f16x8*)(hsrc + n * HP + quad * 8 + 32);
                f32x4 acc[4];
                #pragma unroll
                for (int g_ = 0; g_ < 4; ++g_) {
                    f32x4 a = __builtin_amdgcn_mfma_f32_16x16x32_f16(axf[g_], bx, biasf[g_], 0, 0, 0);
                    a = __builtin_amdgcn_mfma_f32_16x16x32_f16(whi[g_][0], bh0, a, 0, 0, 0);
                    a = __builtin_amdgcn_mfma_f32_16x16x32_f16(wlo[g_][0], bh0, a, 0, 0, 0);
                    a = __builtin_amdgcn_mfma_f32_16x16x32_f16(whi[g_][1], bh1, a, 0, 0, 0);
                    a = __builtin_amdgcn_mfma_f32_16x16x32_f16(wlo[g_][1], bh1, a, 0, 0, 0);
                    acc[g_] = a;
                }
                f16x4 hv;
                #pragma unroll
                for (int r = 0; r < 4; ++r) {
                    const float is = sigmoidf_(acc[0][r]);
                    const float fs = sigmoidf_(acc[1][r]);
                    const float gt = tanhf_(acc[2][r]);
                    const float os = sigmoidf_(acc[3][r]);
                    creg[r] = fs * creg[r] + is * gt;
                    hv[r] = (_Float16)(os * tanhf_(creg[r]));
                }
                *(f16x4*)(h1T[t & 1] + n * HP + 16 * w + quad * 4) = hv;
            }
        } else if (group == 1) {
            if (t >= 1 && t <= TT) {
                const _Float16* hsrc = h1T[(t + 1) & 1];
                const f16x8 bh0 = *(const f16x8*)(hsrc + n * HP + quad * 8);
                const f16x8 bh1 = *(const f16x8*)(hsrc + n * HP + quad * 8 + 32);
                #pragma unroll
                for (int g_ = 0; g_ < 4; ++g_) {
                    f32x4 a = {0.f, 0.f, 0.f, 0.f};
                    a = __builtin_amdgcn_mfma_f32_16x16x32_f16(whi[g_][0], bh0, a, 0, 0, 0);
                    a = __builtin_amdgcn_mfma_f32_16x16x32_f16(wlo[g_][0], bh0, a, 0, 0, 0);
                    a = __builtin_amdgcn_mfma_f32_16x16x32_f16(whi[g_][1], bh1, a, 0, 0, 0);
                    a = __builtin_amdgcn_mfma_f32_16x16x32_f16(wlo[g_][1], bh1, a, 0, 0, 0);
                    pis[t & 1][(w * 4 + g_) * 64 + lane] = a;
                }
            }
        } else {
            if (t >= 2) {
                const _Float16* hsrc = h2T[(t + 1) & 1];
                const f16x8 bh0 = *(const f16x8*)(hsrc + n * HP + quad * 8);
                const f16x8 bh1 = *(const f16x8*)(hsrc + n * HP + quad * 8 + 32);
                f32x4 acc[4];
                #pragma unroll
                for (int g_ = 0; g_ < 4; ++g_) {
                    f32x4 a = __builtin_amdgcn_mfma_f32_16x16x32_f16(whi[g_][0], bh0, biasf[g_], 0, 0, 0);
                    a = __builtin_amdgcn_mfma_f32_16x16x32_f16(wlo[g_][0], bh0, a, 0, 0, 0);
                    a = __builtin_amdgcn_mfma_f32_16x16x32_f16(whi[g_][1], bh1, a, 0, 0, 0);
                    a = __builtin_amdgcn_mfma_f32_16x16x32_f16(wlo[g_][1], bh1, a, 0, 0, 0);
                    acc[g_] = a + pis[(t + 1) & 1][(w * 4 + g_) * 64 + lane];
                }
                f16x4 hv;
                f32x4 hf;
                #pragma unroll
                for (int r = 0; r < 4; ++r) {
                    const float is = sigmoidf_(acc[0][r]);
                    const float fs = sigmoidf_(acc[1][r]);
                    const float gt = tanhf_(acc[2][r]);
                    const float os = sigmoidf_(acc[3][r]);
                    creg[r] = fs * creg[r] + is * gt;
                    const float h = os * tanhf_(creg[r]);
                    hf[r] = h;
                    hv[r] = (_Float16)h;
                }
                *(f16x4*)(h2T[t & 1] + n * HP + 16 * w + quad * 4) = hv;
                if (t == TT + 1 && n < 4) {            // final h2 in fp32 for logits
                    *(f32x4*)(h2f + n * 68 + 16 * w + quad * 4) = hf;
                }
            }
        }
        __syncthreads();
    }

    // ---- epilogue: logits + softmax on fp32 h2 ----
    if (tid < 16) {
        const int b = tid & 3, o = tid >> 2;
        float acc = b_out[o];
        #pragma unroll
        for (int j = 0; j < HH; ++j)
            acc = fmaf(w_out[o * HH + j], h2f[b * 68 + j], acc);
        lg[b][o] = acc;
    }
    __syncthreads();
    if (tid < NB) {
        const int b = tid;
        const float l0 = lg[b][0], l1 = lg[b][1], l2 = lg[b][2], l3 = lg[b][3];
        const float m  = fmaxf(fmaxf(l0, l1), fmaxf(l2, l3));
        const float e0 = __expf(l0 - m), e1 = __expf(l1 - m);
        const float e2 = __expf(l2 - m), e3 = __expf(l3 - m);
        const float sum = 1.0f / (e0 + e1 + e2 + e3);
        out[(b0 + b) * 4 + 0] = e0 * sum;
        out[(b0 + b) * 4 + 1] = e1 * sum;
        out[(b0 + b) * 4 + 2] = e2 * sum;
        out[(b0 + b) * 4 + 3] = e3 * sum;
    }
}

extern "C" void kernel_launch(void* const* d_in, const int* in_sizes, int n_in,
                              void* d_out, int out_size, void* d_ws, size_t ws_size,
                              hipStream_t stream) {
    const float* x     = (const float*)d_in[0];
    const float* w_ih0 = (const float*)d_in[1];
    const float* w_hh0 = (const float*)d_in[2];
    const float* b_ih0 = (const float*)d_in[3];
    const float* b_hh0 = (const float*)d_in[4];
    const float* w_ih1 = (const float*)d_in[5];
    const float* w_hh1 = (const float*)d_in[6];
    const float* b_ih1 = (const float*)d_in[7];
    const float* b_hh1 = (const float*)d_in[8];
    const float* w_out = (const float*)d_in[9];
    const float* b_out = (const float*)d_in[10];
    float* out = (float*)d_out;

    hipLaunchKernelGGL(lstm_mfma, dim3(NBLK), dim3(768), 0, stream,
                       x, w_ih0, w_hh0, b_ih0, b_hh0,
                       w_ih1, w_hh1, b_ih1, b_hh1,
                       w_out, b_out, out);
}

// Round 6
// 845.430 us; speedup vs baseline: 1.0885x; 1.0885x over previous
//
#include <hip/hip_runtime.h>

#define TT    512
#define HH    64
#define NB    4
#define NBLK  256
#define HP    72    // h^T pitch in f16

typedef _Float16 f16x8 __attribute__((ext_vector_type(8)));
typedef _Float16 f16x4 __attribute__((ext_vector_type(4)));
typedef float    f32x4 __attribute__((ext_vector_type(4)));

__device__ __forceinline__ float sigmoidf_(float x) {
    return 1.0f / (1.0f + __expf(-x));
}
__device__ __forceinline__ float tanhf_(float x) {
    return 1.0f - 2.0f / (1.0f + __expf(2.0f * x));
}

// 256 blocks x 768 threads (12 waves). Block owns 4 batches (cols 0..3 of the
// 16-col MFMA tile). Wave W = tid>>6; group = W>>2 (A/B/C); w = W&3.
// Wave w of a group owns M-tiles {w, w+4, w+8, w+12}: i,f,g,o of unit u land
// in the same lane's accumulators (C/D row = quad*4+reg, col = batch).
// Skew (1 barrier/tick, ticks 0..T+1):
//   A: g1(t) = b1 + W_ih0 x(t) + W_hh0 h1(t-1) -> pointwise -> h1(t)
//   B: pis(t) = b2 + W_ih1 h1(t-1) -> LDS (f32, C-layout)
//   C: g2 = pis(t-1) + W_hh1 h2(t-3) -> pointwise -> h2(t-2)
// Precision: weights plain f16 (|W|<=0.125 -> dot-64 err ~1e-4, no residual
// needed — r5 measured 9.8e-4 WITH residual, h-hop f16 dominates);
// fp32 accum/bias/pointwise/c-state; final h2 fp32 for logits.
__global__ __launch_bounds__(768) void lstm_mfma(
    const float* __restrict__ x,
    const float* __restrict__ w_ih0, const float* __restrict__ w_hh0,
    const float* __restrict__ b_ih0, const float* __restrict__ b_hh0,
    const float* __restrict__ w_ih1, const float* __restrict__ w_hh1,
    const float* __restrict__ b_ih1, const float* __restrict__ b_hh1,
    const float* __restrict__ w_out, const float* __restrict__ b_out,
    float* __restrict__ out)
{
    __shared__ __align__(16) _Float16 h1T[2][16 * HP];  // h1^T [batch][unit] f16
    __shared__ __align__(16) _Float16 h2T[2][16 * HP];  // h2^T
    __shared__ f32x4 pis[2][1024];                      // B->C partial (bias+ih)
    __shared__ float xs[TT * 12];                       // x [t][d][4] fp32
    __shared__ __align__(16) float h2f[16 * 68];        // final h2 fp32
    __shared__ float lg[NB][4];

    const int tid   = threadIdx.x;
    const int group = tid >> 8;          // wave-uniform
    const int w     = (tid >> 6) & 3;    // wave-in-group
    const int lane  = tid & 63;
    const int quad  = lane >> 4;
    const int n     = lane & 15;         // MFMA column = batch slot
    const int b0    = blockIdx.x * NB;

    // ---- persistent weight fragments (f16, no residual) ----
    f16x8 whi[4][2], axf[4];
    f32x4 biasf[4];
    {
        const float* Wm = (group == 0) ? w_hh0 : (group == 1) ? w_ih1 : w_hh1;
        #pragma unroll
        for (int g_ = 0; g_ < 4; ++g_) {
            const int arow = 16 * w + 64 * g_ + n;      // A-frag row m = lane&15
            #pragma unroll
            for (int k0 = 0; k0 < 2; ++k0) {
                const float* p = Wm + arow * HH + quad * 8 + 32 * k0;
                #pragma unroll
                for (int j = 0; j < 8; ++j)
                    whi[g_][k0][j] = (_Float16)p[j];
            }
            #pragma unroll
            for (int r = 0; r < 4; ++r) {               // C/D row = quad*4 + r
                const int crow = 16 * w + 64 * g_ + quad * 4 + r;
                biasf[g_][r] = (group == 0) ? (b_ih0[crow] + b_hh0[crow])
                             : (group == 1) ? (b_ih1[crow] + b_hh1[crow])
                                            : 0.f;
            }
            f16x8 ax;
            #pragma unroll
            for (int j = 0; j < 8; ++j) ax[j] = (_Float16)0.f;
            if (group == 0 && quad == 0) {              // K=3 x-transform
                ax[0] = (_Float16)w_ih0[arow * 3 + 0];
                ax[1] = (_Float16)w_ih0[arow * 3 + 1];
                ax[2] = (_Float16)w_ih0[arow * 3 + 2];
            }
            axf[g_] = ax;
        }
    }

    // ---- LDS init ----
    for (int i = tid; i < 1152; i += 768) {
        ((int*)h1T)[i] = 0;
        ((int*)h2T)[i] = 0;
    }
    for (int i = tid; i < TT * 12; i += 768) {
        const int t = i / 12, rem = i - t * 12;
        const int d = rem >> 2, b = rem & 3;
        xs[i] = x[(size_t)(b0 + b) * (TT * 3) + t * 3 + d];
    }
    __syncthreads();

    float creg[4] = {0.f, 0.f, 0.f, 0.f};

    for (int t = 0; t <= TT + 1; ++t) {
        if (group == 0) {
            if (t < TT) {
                f16x8 bx;
                #pragma unroll
                for (int j = 0; j < 8; ++j) bx[j] = (_Float16)0.f;
                if (quad == 0) {
                    const float* xp = xs + t * 12 + (lane & 3);
                    bx[0] = (_Float16)xp[0];
                    bx[1] = (_Float16)xp[4];
                    bx[2] = (_Float16)xp[8];
                }
                const _Float16* hsrc = h1T[(t + 1) & 1];
                const f16x8 bh0 = *(const f16x8*)(hsrc + n * HP + quad * 8);
                const f16x8 bh1 = *(const f16x8*)(hsrc + n * HP + quad * 8 + 32);
                f32x4 acc[4];
                #pragma unroll
                for (int g_ = 0; g_ < 4; ++g_) {
                    f32x4 a = __builtin_amdgcn_mfma_f32_16x16x32_f16(axf[g_], bx, biasf[g_], 0, 0, 0);
                    a = __builtin_amdgcn_mfma_f32_16x16x32_f16(whi[g_][0], bh0, a, 0, 0, 0);
                    a = __builtin_amdgcn_mfma_f32_16x16x32_f16(whi[g_][1], bh1, a, 0, 0, 0);
                    acc[g_] = a;
                }
                f16x4 hv;
                #pragma unroll
                for (int r = 0; r < 4; ++r) {
                    const float is = sigmoidf_(acc[0][r]);
                    const float fs = sigmoidf_(acc[1][r]);
                    const float gt = tanhf_(acc[2][r]);
                    const float os = sigmoidf_(acc[3][r]);
                    creg[r] = fs * creg[r] + is * gt;
                    hv[r] = (_Float16)(os * tanhf_(creg[r]));
                }
                *(f16x4*)(h1T[t & 1] + n * HP + 16 * w + quad * 4) = hv;
            }
        } else if (group == 1) {
            if (t >= 1 && t <= TT) {
                const _Float16* hsrc = h1T[(t + 1) & 1];
                const f16x8 bh0 = *(const f16x8*)(hsrc + n * HP + quad * 8);
                const f16x8 bh1 = *(const f16x8*)(hsrc + n * HP + quad * 8 + 32);
                #pragma unroll
                for (int g_ = 0; g_ < 4; ++g_) {
                    f32x4 a = __builtin_amdgcn_mfma_f32_16x16x32_f16(whi[g_][0], bh0, biasf[g_], 0, 0, 0);
                    a = __builtin_amdgcn_mfma_f32_16x16x32_f16(whi[g_][1], bh1, a, 0, 0, 0);
                    pis[t & 1][(w * 4 + g_) * 64 + lane] = a;
                }
            }
        } else {
            if (t >= 2) {
                const _Float16* hsrc = h2T[(t + 1) & 1];
                const f16x8 bh0 = *(const f16x8*)(hsrc + n * HP + quad * 8);
                const f16x8 bh1 = *(const f16x8*)(hsrc + n * HP + quad * 8 + 32);
                f32x4 acc[4];
                #pragma unroll
                for (int g_ = 0; g_ < 4; ++g_) {
                    f32x4 a = pis[(t + 1) & 1][(w * 4 + g_) * 64 + lane];
                    a = __builtin_amdgcn_mfma_f32_16x16x32_f16(whi[g_][0], bh0, a, 0, 0, 0);
                    a = __builtin_amdgcn_mfma_f32_16x16x32_f16(whi[g_][1], bh1, a, 0, 0, 0);
                    acc[g_] = a;
                }
                f16x4 hv;
                f32x4 hf;
                #pragma unroll
                for (int r = 0; r < 4; ++r) {
                    const float is = sigmoidf_(acc[0][r]);
                    const float fs = sigmoidf_(acc[1][r]);
                    const float gt = tanhf_(acc[2][r]);
                    const float os = sigmoidf_(acc[3][r]);
                    creg[r] = fs * creg[r] + is * gt;
                    const float h = os * tanhf_(creg[r]);
                    hf[r] = h;
                    hv[r] = (_Float16)h;
                }
                *(f16x4*)(h2T[t & 1] + n * HP + 16 * w + quad * 4) = hv;
                if (t == TT + 1 && n < 4) {
                    *(f32x4*)(h2f + n * 68 + 16 * w + quad * 4) = hf;
                }
            }
        }
        __syncthreads();
    }

    // ---- epilogue: logits + softmax on fp32 h2 ----
    if (tid < 16) {
        const int b = tid & 3, o = tid >> 2;
        float acc = b_out[o];
        #pragma unroll
        for (int j = 0; j < HH; ++j)
            acc = fmaf(w_out[o * HH + j], h2f[b * 68 + j], acc);
        lg[b][o] = acc;
    }
    __syncthreads();
    if (tid < NB) {
        const int b = tid;
        const float l0 = lg[b][0], l1 = lg[b][1], l2 = lg[b][2], l3 = lg[b][3];
        const float m  = fmaxf(fmaxf(l0, l1), fmaxf(l2, l3));
        const float e0 = __expf(l0 - m), e1 = __expf(l1 - m);
        const float e2 = __expf(l2 - m), e3 = __expf(l3 - m);
        const float sum = 1.0f / (e0 + e1 + e2 + e3);
        out[(b0 + b) * 4 + 0] = e0 * sum;
        out[(b0 + b) * 4 + 1] = e1 * sum;
        out[(b0 + b) * 4 + 2] = e2 * sum;
        out[(b0 + b) * 4 + 3] = e3 * sum;
    }
}

extern "C" void kernel_launch(void* const* d_in, const int* in_sizes, int n_in,
                              void* d_out, int out_size, void* d_ws, size_t ws_size,
                              hipStream_t stream) {
    const float* x     = (const float*)d_in[0];
    const float* w_ih0 = (const float*)d_in[1];
    const float* w_hh0 = (const float*)d_in[2];
    const float* b_ih0 = (const float*)d_in[3];
    const float* b_hh0 = (const float*)d_in[4];
    const float* w_ih1 = (const float*)d_in[5];
    const float* w_hh1 = (const float*)d_in[6];
    const float* b_ih1 = (const float*)d_in[7];
    const float* b_hh1 = (const float*)d_in[8];
    const float* w_out = (const float*)d_in[9];
    const float* b_out = (const float*)d_in[10];
    float* out = (float*)d_out;

    hipLaunchKernelGGL(lstm_mfma, dim3(NBLK), dim3(768), 0, stream,
                       x, w_ih0, w_hh0, b_ih0, b_hh0,
                       w_ih1, w_hh1, b_ih1, b_hh1,
                       w_out, b_out, out);
}

// Round 7
// 506.199 us; speedup vs baseline: 1.8179x; 1.6702x over previous
//
#include <hip/hip_runtime.h>

#define TT    512
#define HH    64
#define NB    4
#define NBLK  256
#define HP    72    // h^T pitch in f16

typedef _Float16 f16x8 __attribute__((ext_vector_type(8)));
typedef _Float16 f16x4 __attribute__((ext_vector_type(4)));
typedef float    f32x4 __attribute__((ext_vector_type(4)));

__device__ __forceinline__ float sigmoidf_(float x) {
    return 1.0f / (1.0f + __expf(-x));
}
__device__ __forceinline__ float tanhf_(float x) {
    return 1.0f - 2.0f / (1.0f + __expf(2.0f * x));
}

// 256 blocks x 768 threads (12 waves). Block owns 4 batches (cols 0..3 of the
// 16-col MFMA tile). Wave W = tid>>6; group = W>>2 (A/B/C); w = W&3.
// Wave w of a group owns M-tiles {w, w+4, w+8, w+12} (gate g_ of units
// [16w,16w+16)). After MFMA, a same-wave LDS transpose (cellbuf) redistributes
// the 64 REAL cells (16 units x 4 batches) to one cell per lane, so the
// pointwise costs 10 transcendentals/lane instead of 40 (r6 ran 4 cells/lane,
// 12 of 16 columns garbage).
// Skew (1 barrier/tick, ticks 0..T+1):
//   A: g1(t) = b1 + W_ih0 x(t) + W_hh0 h1(t-1) -> pointwise -> h1(t)
//   B: pis(t) = b2 + W_ih1 h1(t-1) -> LDS (f32, C-layout)
//   C: g2 = pis(t-1) + W_hh1 h2(t-3) -> pointwise -> h2(t-2)
// Precision: f16 weights/h-hop, fp32 accum/bias/pointwise/c (r6: 9.8e-4).
__global__ __launch_bounds__(768) void lstm_mfma(
    const float* __restrict__ x,
    const float* __restrict__ w_ih0, const float* __restrict__ w_hh0,
    const float* __restrict__ b_ih0, const float* __restrict__ b_hh0,
    const float* __restrict__ w_ih1, const float* __restrict__ w_hh1,
    const float* __restrict__ b_ih1, const float* __restrict__ b_hh1,
    const float* __restrict__ w_out, const float* __restrict__ b_out,
    float* __restrict__ out)
{
    __shared__ __align__(16) _Float16 h1T[2][16 * HP];  // h1^T [batch][unit] f16
    __shared__ __align__(16) _Float16 h2T[2][16 * HP];  // h2^T
    __shared__ f32x4 pis[2][1024];                      // B->C partial (bias+ih)
    __shared__ float xs[TT * 12];                       // x [t][d][4] fp32
    __shared__ __align__(16) f32x4 cellA[4][64];        // A gate transpose, per wave
    __shared__ __align__(16) f32x4 cellC[4][64];        // C gate transpose, per wave
    __shared__ __align__(16) float h2f[16 * 68];        // final h2 fp32
    __shared__ float lg[NB][4];

    const int tid   = threadIdx.x;
    const int group = tid >> 8;          // wave-uniform
    const int w     = (tid >> 6) & 3;    // wave-in-group
    const int lane  = tid & 63;
    const int quad  = lane >> 4;
    const int n     = lane & 15;         // MFMA column = batch slot
    const int b0    = blockIdx.x * NB;

    // cell owned by this lane after the transpose: unit 16w + (lane>>2), batch lane&3
    const int cu    = lane >> 2;                         // unit-in-wave 0..15
    const int cb    = lane & 3;                          // batch 0..3
    const int rdslot = lane ^ ((lane >> 4) << 2);        // XOR-swizzled read slot

    // ---- persistent weight fragments (f16, no residual) ----
    f16x8 whi[4][2], axf[4];
    f32x4 biasf[4];
    {
        const float* Wm = (group == 0) ? w_hh0 : (group == 1) ? w_ih1 : w_hh1;
        #pragma unroll
        for (int g_ = 0; g_ < 4; ++g_) {
            const int arow = 16 * w + 64 * g_ + n;      // A-frag row m = lane&15
            #pragma unroll
            for (int k0 = 0; k0 < 2; ++k0) {
                const float* p = Wm + arow * HH + quad * 8 + 32 * k0;
                #pragma unroll
                for (int j = 0; j < 8; ++j)
                    whi[g_][k0][j] = (_Float16)p[j];
            }
            #pragma unroll
            for (int r = 0; r < 4; ++r) {               // C/D row = quad*4 + r
                const int crow = 16 * w + 64 * g_ + quad * 4 + r;
                biasf[g_][r] = (group == 0) ? (b_ih0[crow] + b_hh0[crow])
                             : (group == 1) ? (b_ih1[crow] + b_hh1[crow])
                                            : 0.f;
            }
            f16x8 ax;
            #pragma unroll
            for (int j = 0; j < 8; ++j) ax[j] = (_Float16)0.f;
            if (group == 0 && quad == 0) {              // K=3 x-transform
                ax[0] = (_Float16)w_ih0[arow * 3 + 0];
                ax[1] = (_Float16)w_ih0[arow * 3 + 1];
                ax[2] = (_Float16)w_ih0[arow * 3 + 2];
            }
            axf[g_] = ax;
        }
    }

    // ---- LDS init ----
    for (int i = tid; i < 1152; i += 768) {
        ((int*)h1T)[i] = 0;
        ((int*)h2T)[i] = 0;
    }
    for (int i = tid; i < TT * 12; i += 768) {
        const int t = i / 12, rem = i - t * 12;
        const int d = rem >> 2, b = rem & 3;
        xs[i] = x[(size_t)(b0 + b) * (TT * 3) + t * 3 + d];
    }
    __syncthreads();

    float creg = 0.f;     // A: c1 of (unit 16w+cu, batch cb); C: c2 of same

    for (int t = 0; t <= TT + 1; ++t) {
        if (group == 0) {
            if (t < TT) {
                f16x8 bx;
                #pragma unroll
                for (int j = 0; j < 8; ++j) bx[j] = (_Float16)0.f;
                if (quad == 0) {
                    const float* xp = xs + t * 12 + (lane & 3);
                    bx[0] = (_Float16)xp[0];
                    bx[1] = (_Float16)xp[4];
                    bx[2] = (_Float16)xp[8];
                }
                const _Float16* hsrc = h1T[(t + 1) & 1];
                const f16x8 bh0 = *(const f16x8*)(hsrc + n * HP + quad * 8);
                const f16x8 bh1 = *(const f16x8*)(hsrc + n * HP + quad * 8 + 32);
                f32x4 acc[4];
                #pragma unroll
                for (int g_ = 0; g_ < 4; ++g_) {
                    f32x4 a = __builtin_amdgcn_mfma_f32_16x16x32_f16(axf[g_], bx, biasf[g_], 0, 0, 0);
                    a = __builtin_amdgcn_mfma_f32_16x16x32_f16(whi[g_][0], bh0, a, 0, 0, 0);
                    a = __builtin_amdgcn_mfma_f32_16x16x32_f16(whi[g_][1], bh1, a, 0, 0, 0);
                    acc[g_] = a;
                }
                // same-wave transpose: only real batch columns write
                if (n < 4) {
                    #pragma unroll
                    for (int r = 0; r < 4; ++r) {
                        const int slot = (16 * quad + 4 * r + n) ^ (quad << 2);
                        f32x4 v = {acc[0][r], acc[1][r], acc[2][r], acc[3][r]};
                        cellA[w][slot] = v;
                    }
                }
                const f32x4 gate = cellA[w][rdslot];     // compiler emits lgkmcnt wait
                const float is = sigmoidf_(gate[0]);
                const float fs = sigmoidf_(gate[1]);
                const float gt = tanhf_(gate[2]);
                const float os = sigmoidf_(gate[3]);
                creg = fs * creg + is * gt;
                h1T[t & 1][cb * HP + 16 * w + cu] = (_Float16)(os * tanhf_(creg));
            }
        } else if (group == 1) {
            if (t >= 1 && t <= TT) {
                const _Float16* hsrc = h1T[(t + 1) & 1];
                const f16x8 bh0 = *(const f16x8*)(hsrc + n * HP + quad * 8);
                const f16x8 bh1 = *(const f16x8*)(hsrc + n * HP + quad * 8 + 32);
                #pragma unroll
                for (int g_ = 0; g_ < 4; ++g_) {
                    f32x4 a = __builtin_amdgcn_mfma_f32_16x16x32_f16(whi[g_][0], bh0, biasf[g_], 0, 0, 0);
                    a = __builtin_amdgcn_mfma_f32_16x16x32_f16(whi[g_][1], bh1, a, 0, 0, 0);
                    pis[t & 1][(w * 4 + g_) * 64 + lane] = a;
                }
            }
        } else {
            if (t >= 2) {
                const _Float16* hsrc = h2T[(t + 1) & 1];
                const f16x8 bh0 = *(const f16x8*)(hsrc + n * HP + quad * 8);
                const f16x8 bh1 = *(const f16x8*)(hsrc + n * HP + quad * 8 + 32);
                f32x4 acc[4];
                #pragma unroll
                for (int g_ = 0; g_ < 4; ++g_) {
                    f32x4 a = pis[(t + 1) & 1][(w * 4 + g_) * 64 + lane];
                    a = __builtin_amdgcn_mfma_f32_16x16x32_f16(whi[g_][0], bh0, a, 0, 0, 0);
                    a = __builtin_amdgcn_mfma_f32_16x16x32_f16(whi[g_][1], bh1, a, 0, 0, 0);
                    acc[g_] = a;
                }
                if (n < 4) {
                    #pragma unroll
                    for (int r = 0; r < 4; ++r) {
                        const int slot = (16 * quad + 4 * r + n) ^ (quad << 2);
                        f32x4 v = {acc[0][r], acc[1][r], acc[2][r], acc[3][r]};
                        cellC[w][slot] = v;
                    }
                }
                const f32x4 gate = cellC[w][rdslot];
                const float is = sigmoidf_(gate[0]);
                const float fs = sigmoidf_(gate[1]);
                const float gt = tanhf_(gate[2]);
                const float os = sigmoidf_(gate[3]);
                creg = fs * creg + is * gt;
                const float h = os * tanhf_(creg);
                h2T[t & 1][cb * HP + 16 * w + cu] = (_Float16)h;
                if (t == TT + 1) {
                    h2f[cb * 68 + 16 * w + cu] = h;      // final h2 fp32 for logits
                }
            }
        }
        __syncthreads();
    }

    // ---- epilogue: logits + softmax on fp32 h2 ----
    if (tid < 16) {
        const int b = tid & 3, o = tid >> 2;
        float acc = b_out[o];
        #pragma unroll
        for (int j = 0; j < HH; ++j)
            acc = fmaf(w_out[o * HH + j], h2f[b * 68 + j], acc);
        lg[b][o] = acc;
    }
    __syncthreads();
    if (tid < NB) {
        const int b = tid;
        const float l0 = lg[b][0], l1 = lg[b][1], l2 = lg[b][2], l3 = lg[b][3];
        const float m  = fmaxf(fmaxf(l0, l1), fmaxf(l2, l3));
        const float e0 = __expf(l0 - m), e1 = __expf(l1 - m);
        const float e2 = __expf(l2 - m), e3 = __expf(l3 - m);
        const float sum = 1.0f / (e0 + e1 + e2 + e3);
        out[(b0 + b) * 4 + 0] = e0 * sum;
        out[(b0 + b) * 4 + 1] = e1 * sum;
        out[(b0 + b) * 4 + 2] = e2 * sum;
        out[(b0 + b) * 4 + 3] = e3 * sum;
    }
}

extern "C" void kernel_launch(void* const* d_in, const int* in_sizes, int n_in,
                              void* d_out, int out_size, void* d_ws, size_t ws_size,
                              hipStream_t stream) {
    const float* x     = (const float*)d_in[0];
    const float* w_ih0 = (const float*)d_in[1];
    const float* w_hh0 = (const float*)d_in[2];
    const float* b_ih0 = (const float*)d_in[3];
    const float* b_hh0 = (const float*)d_in[4];
    const float* w_ih1 = (const float*)d_in[5];
    const float* w_hh1 = (const float*)d_in[6];
    const float* b_ih1 = (const float*)d_in[7];
    const float* b_hh1 = (const float*)d_in[8];
    const float* w_out = (const float*)d_in[9];
    const float* b_out = (const float*)d_in[10];
    float* out = (float*)d_out;

    hipLaunchKernelGGL(lstm_mfma, dim3(NBLK), dim3(768), 0, stream,
                       x, w_ih0, w_hh0, b_ih0, b_hh0,
                       w_ih1, w_hh1, b_ih1, b_hh1,
                       w_out, b_out, out);
}